// Round 2
// baseline (670.905 us; speedup 1.0000x reference)
//
#include <hip/hip_runtime.h>
#include <stdint.h>

#define B_DIM 2
#define M_DIM 65536
#define E_DIM 512
#define K_DIM 256

typedef __bf16 bf16_t;
typedef __bf16 bf16x8 __attribute__((ext_vector_type(8)));
typedef float  f32x4  __attribute__((ext_vector_type(4)));
typedef float  f32x16 __attribute__((ext_vector_type(16)));
typedef int    i32x8  __attribute__((ext_vector_type(8)));

typedef const __attribute__((address_space(1))) void* gas_ptr;
typedef __attribute__((address_space(3))) void* las_ptr;

__device__ __forceinline__ void async_load16(const void* g, void* l) {
    __builtin_amdgcn_global_load_lds((gas_ptr)g, (las_ptr)l, 16, 0, 0);
}

__device__ __forceinline__ unsigned short bf16_bits(float f) {
    return __builtin_bit_cast(unsigned short, (__bf16)f);
}
__device__ __forceinline__ unsigned int pack2(float lo, float hi) {
    return (unsigned int)bf16_bits(lo) | ((unsigned int)bf16_bits(hi) << 16);
}
__device__ __forceinline__ float bf16u_to_f32(unsigned short us) {
    return __builtin_bit_cast(float, (unsigned)us << 16);
}
// pack 8 floats -> 8 fp8 e4m3 bytes (uint2)
__device__ __forceinline__ uint2 pack8_fp8(const float* f) {
    int lo = __builtin_amdgcn_cvt_pk_fp8_f32(f[0], f[1], 0, false);
    lo = __builtin_amdgcn_cvt_pk_fp8_f32(f[2], f[3], lo, true);
    int hi = __builtin_amdgcn_cvt_pk_fp8_f32(f[4], f[5], 0, false);
    hi = __builtin_amdgcn_cvt_pk_fp8_f32(f[6], f[7], hi, true);
    return make_uint2((unsigned)lo, (unsigned)hi);
}

// ---------------- K0: cast W (fp32 -> bf16) ----------------
__global__ __launch_bounds__(256) void cast_w(const float* __restrict__ W, bf16_t* __restrict__ Wb) {
    int idx = blockIdx.x * 256 + threadIdx.x;            // 32768 float4 chunks
    float4 v = ((const float4*)W)[idx];
    ((uint2*)Wb)[idx] = make_uint2(pack2(v.x, v.y), pack2(v.z, v.w));
}

// ---------------- K1: fused GEMM1(bf16) + exp + colsum-partials + fp8 emit of xT, pb ----------------
// BM=128 m-tile, 512 threads = 8 waves (wave w: wk=w>>1 k-quarter, wm=w&1 m-half), BK=64 over e.
// Per iter: [cvt+write x(ke) -> Blds dbuf] barrierA [A-DMA issue] barrierB
//           [x-prefetch(ke+1) -> regs: HBM latency hides under compute] [frags+MFMA+emit].
__global__ __launch_bounds__(512, 4) void gemm1_exp_t(const float* __restrict__ x, const bf16_t* __restrict__ Wb,
                                                      unsigned char* __restrict__ pb8, float* __restrict__ psums,
                                                      unsigned char* __restrict__ xT8) {
    int gid = blockIdx.x;
    int mt = gid & 511;
    int b  = gid >> 9;
    int m0 = mt * 128;
    int t = threadIdx.x, lane = t & 63, w = t >> 6;
    int wk = w >> 1, wm = w & 1;

    __shared__ __align__(16) char smem[65536];
    bf16_t* Alds = (bf16_t*)smem;              // 256 k-rows x 64 e = 32 KB (K-loop)
    bf16_t* Blds = (bf16_t*)(smem + 32768);    // dbuf: 2 x (128 m-rows x 64 e) = 2 x 16 KB
    bf16_t* Elds = (bf16_t*)smem;              // 256 k x 128 m = 64 KB (epilogue, aliases all)

    const float* xb = x + ((size_t)b * M_DIM + m0) * E_DIM;

    f32x4 zero = {0.f, 0.f, 0.f, 0.f};
    f32x4 acc[4][4];
#pragma unroll
    for (int i = 0; i < 4; ++i)
#pragma unroll
        for (int j = 0; j < 4; ++j) acc[i][j] = zero;

    // B staging: thread t -> m-row r=t>>2 (0..127), LDS slots {t&3, 4+(t&3)}
    int bst_r = t >> 2, bst_s0 = t & 3;
    int ge0 = bst_s0 ^ (bst_r & 7);
    int ge1 = (bst_s0 + 4) ^ (bst_r & 7);

    int q = lane >> 4, r15 = lane & 15;

    // prologue: prefetch x(ke=0) into regs
    float4 xr0, xr1, xr2, xr3;
    {
        const float4* f0 = (const float4*)(xb + (size_t)bst_r * E_DIM + ge0 * 8);
        const float4* f1 = (const float4*)(xb + (size_t)bst_r * E_DIM + ge1 * 8);
        xr0 = f0[0]; xr1 = f0[1];
        xr2 = f1[0]; xr3 = f1[1];
    }

    for (int ke = 0; ke < 8; ++ke) {
        int e0 = ke * 64;
        int cur = ke & 1;
        bf16_t* Bl = Blds + cur * 8192;

        // --- cvt + write x(ke) from regs into idle B buffer (pre-barrier) ---
        *(uint4*)(Bl + bst_r * 64 + bst_s0 * 8) =
            make_uint4(pack2(xr0.x, xr0.y), pack2(xr0.z, xr0.w), pack2(xr1.x, xr1.y), pack2(xr1.z, xr1.w));
        *(uint4*)(Bl + bst_r * 64 + (bst_s0 + 4) * 8) =
            make_uint4(pack2(xr2.x, xr2.y), pack2(xr2.z, xr2.w), pack2(xr3.x, xr3.y), pack2(xr3.z, xr3.w));

        __syncthreads();   // barrier A: prev compute done (Alds free), B-writes visible

        // --- A tile: 256 k-rows x 64 e via global_load_lds (swizzle on global granule) ---
#pragma unroll
        for (int is = 0; is < 4; ++is) {
            int c = is * 512 + t;          // 16B slot id 0..2047, lane-linear LDS dst
            int row = c >> 3, sl = c & 7;
            int ge = sl ^ (row & 7);
            async_load16(Wb + (size_t)row * E_DIM + e0 + ge * 8, Alds + c * 8);
        }
        __syncthreads();   // barrier B: A-DMA drained

        // --- issue x-prefetch for ke+1 (latency hides under compute below) ---
        if (ke < 7) {
            const float4* f0 = (const float4*)(xb + (size_t)bst_r * E_DIM + (e0 + 64) + ge0 * 8);
            const float4* f1 = (const float4*)(xb + (size_t)bst_r * E_DIM + (e0 + 64) + ge1 * 8);
            xr0 = f0[0]; xr1 = f0[1];
            xr2 = f1[0]; xr3 = f1[1];
        }

        // --- compute ---
#pragma unroll
        for (int h = 0; h < 2; ++h) {
            bf16x8 af[4], bfr[4];
#pragma unroll
            for (int i = 0; i < 4; ++i) {
                int r = wk * 64 + i * 16 + r15;
                int sl = (h * 4 + q) ^ (r & 7);
                af[i] = *(const bf16x8*)(Alds + r * 64 + sl * 8);
            }
#pragma unroll
            for (int j = 0; j < 4; ++j) {
                int r = wm * 64 + j * 16 + r15;
                int sl = (h * 4 + q) ^ (r & 7);
                bfr[j] = *(const bf16x8*)(Bl + r * 64 + sl * 8);
            }
#pragma unroll
            for (int i = 0; i < 4; ++i)
#pragma unroll
                for (int j = 0; j < 4; ++j)
                    acc[i][j] = __builtin_amdgcn_mfma_f32_16x16x32_bf16(af[i], bfr[j], acc[i][j], 0, 0, 0);
        }

        // --- xT8 emit: read B-tile columns (rotated m -> conflict-free), cvt to fp8, store ---
        {
            const unsigned short* Bs = (const unsigned short*)Bl;
            int l7 = t & 7;
            int mg = l7 + ((t >> 8) << 3);      // m-granule 0..15
            int mbase = mg * 8;
            int ebase = (t >> 3) & 31;          // 0..31
#pragma unroll
            for (int p = 0; p < 2; ++p) {
                int ecol = p * 32 + ebase;
                float f[8];
#pragma unroll
                for (int s = 0; s < 8; ++s) {
                    int mmr = (s + l7) & 7;     // rotated m&7 -> conflict-free
                    int sl = (ecol >> 3) ^ mmr;
                    f[mmr] = bf16u_to_f32(Bs[(mbase + mmr) * 64 + sl * 8 + (ecol & 7)]);
                }
                *(uint2*)(xT8 + ((size_t)(b * E_DIM + e0 + ecol)) * M_DIM + m0 + mbase) = pack8_fp8(f);
            }
        }
    }
    __syncthreads();   // all compute/emit done before Elds (aliasing) writes

    // ---- epilogue: p = exp(score); per-k partial sums; pb8 via LDS repack ----
    int cc = lane & 15;
    float ksum[4][4];   // [i][p]
#pragma unroll
    for (int i = 0; i < 4; ++i)
#pragma unroll
        for (int p = 0; p < 4; ++p) ksum[i][p] = 0.f;

#pragma unroll
    for (int i = 0; i < 4; ++i) {
        int kr = wk * 64 + i * 16 + q * 4;
#pragma unroll
        for (int j = 0; j < 4; ++j) {
            int colb = wm * 64 + j * 16 + cc;
            int g = colb >> 3, off = colb & 7;
#pragma unroll
            for (int p = 0; p < 4; ++p) {
                float v = __expf(acc[i][j][p]);
                ksum[i][p] += v;
                int k = kr + p;
                Elds[k * 128 + ((g ^ (k & 15)) * 8) + off] = (bf16_t)v;
            }
        }
    }
    // reduce ksum across the 16 cc-lanes of each quad-group (sums this wave's 64-m half)
#pragma unroll
    for (int mask = 1; mask < 16; mask <<= 1)
#pragma unroll
        for (int i = 0; i < 4; ++i)
#pragma unroll
            for (int p = 0; p < 4; ++p)
                ksum[i][p] += __shfl_xor(ksum[i][p], mask, 64);
    if (cc == 0) {
        // psums entry per (m-half): layout [b][1024][256] preserved (mt*2 + wm)
        float* pp = psums + ((size_t)b * 1024 + mt * 2 + wm) * 256;
#pragma unroll
        for (int i = 0; i < 4; ++i)
#pragma unroll
            for (int p = 0; p < 4; ++p)
                pp[wk * 64 + i * 16 + q * 4 + p] = ksum[i][p];
    }
    __syncthreads();

    // cooperative pb8 store: 8 passes, thread covers 16B (bf16 granule pair) of row p*32+(t>>4)
    {
        int g16 = t & 15, rsub = t >> 4;   // rsub 0..31
        unsigned char* dstb = pb8 + (size_t)b * K_DIM * M_DIM + m0;
#pragma unroll
        for (int p = 0; p < 8; ++p) {
            int k = p * 32 + rsub;
            uint4 vv = *(const uint4*)(Elds + k * 128 + ((g16 ^ (k & 15)) * 8));
            const unsigned short* us = (const unsigned short*)&vv;
            float f[8];
#pragma unroll
            for (int s = 0; s < 8; ++s) f[s] = bf16u_to_f32(us[s]);
            *(uint2*)(dstb + (size_t)k * M_DIM + g16 * 8) = pack8_fp8(f);
        }
    }
}

// ---------------- K2: GEMM2 fp8 (MX-scaled, scale=1.0), BK=64 ----------------
// part[bid][kl][el] = sum_m pb[k][m]*xT[e][m]
// block: 128k x 128e, 4 waves (2x2), m-chunk = 1024 (64 chunks -> 1024 blocks, 4/CU), 16 iters.
__global__ __launch_bounds__(256, 4) void gemm2(const unsigned char* __restrict__ pb8, const unsigned char* __restrict__ xT8,
                                                float* __restrict__ part) {
    int bid = blockIdx.x;
    int kt = bid & 1, et = (bid >> 1) & 3, ch = (bid >> 3) & 63, b = bid >> 9;
    int t = threadIdx.x, lane = t & 63, w = t >> 6;
    int wk = w & 1, we = w >> 1;

    __shared__ __align__(16) unsigned char Alds[2][128 * 64];   // 2 x 8 KB
    __shared__ __align__(16) unsigned char Blds[2][128 * 64];   // 2 x 8 KB

    const unsigned char* Ab = pb8 + ((size_t)(b * K_DIM + kt * 128)) * M_DIM + ch * 1024;
    const unsigned char* Bb = xT8 + ((size_t)(b * E_DIM + et * 128)) * M_DIM + ch * 1024;

    f32x16 acc[2][2];
#pragma unroll
    for (int i = 0; i < 2; ++i)
#pragma unroll
        for (int j = 0; j < 2; ++j)
#pragma unroll
            for (int p = 0; p < 16; ++p) acc[i][j][p] = 0.f;

    int l31 = lane & 31, g = lane >> 5;

    auto STAGE = [&](int buf, int m0) {
#pragma unroll
        for (int is = 0; is < 2; ++is) {
            int c = is * 256 + t;          // 16B slot id 0..511, lane-linear LDS dst
            int row = c >> 2, a = c & 3;
            int sr = (row & 3) ^ ((row >> 2) & 3);
            int bsl = a ^ sr;              // phys slot a holds logical slot a^sr
            async_load16(Ab + (size_t)row * M_DIM + m0 + bsl * 16, &Alds[buf][c * 16]);
            async_load16(Bb + (size_t)row * M_DIM + m0 + bsl * 16, &Blds[buf][c * 16]);
        }
    };

    STAGE(0, 0);
    __syncthreads();                       // drain prologue staging

    for (int km = 0; km < 16; ++km) {
        int cur = km & 1;
        if (km + 1 < 16) STAGE(cur ^ 1, (km + 1) * 64);   // issue next tile early

        i32x8 av[2], bv[2];
#pragma unroll
        for (int i = 0; i < 2; ++i) {
            int r = wk * 64 + i * 32 + l31;
            int sr = (r & 3) ^ ((r >> 2) & 3);
            int4 lo = *(const int4*)(&Alds[cur][r * 64 + (((2 * g) ^ sr) * 16)]);
            int4 hi = *(const int4*)(&Alds[cur][r * 64 + (((2 * g + 1) ^ sr) * 16)]);
            av[i][0] = lo.x; av[i][1] = lo.y; av[i][2] = lo.z; av[i][3] = lo.w;
            av[i][4] = hi.x; av[i][5] = hi.y; av[i][6] = hi.z; av[i][7] = hi.w;
        }
#pragma unroll
        for (int j = 0; j < 2; ++j) {
            int r = we * 64 + j * 32 + l31;
            int sr = (r & 3) ^ ((r >> 2) & 3);
            int4 lo = *(const int4*)(&Blds[cur][r * 64 + (((2 * g) ^ sr) * 16)]);
            int4 hi = *(const int4*)(&Blds[cur][r * 64 + (((2 * g + 1) ^ sr) * 16)]);
            bv[j][0] = lo.x; bv[j][1] = lo.y; bv[j][2] = lo.z; bv[j][3] = lo.w;
            bv[j][4] = hi.x; bv[j][5] = hi.y; bv[j][6] = hi.z; bv[j][7] = hi.w;
        }

        __builtin_amdgcn_s_setprio(1);
#pragma unroll
        for (int i = 0; i < 2; ++i)
#pragma unroll
            for (int j = 0; j < 2; ++j)
                acc[i][j] = __builtin_amdgcn_mfma_scale_f32_32x32x64_f8f6f4(
                    av[i], bv[j], acc[i][j],
                    0 /*cbsz: fp8 e4m3*/, 0 /*blgp: fp8 e4m3*/,
                    0, 0x7f7f7f7f /*scale A = 1.0*/,
                    0, 0x7f7f7f7f /*scale B = 1.0*/);
        __builtin_amdgcn_s_setprio(0);

        __syncthreads();   // waves done reading buf[cur]; next-tile staging drained
    }

    // C/D 32x32 layout: col = lane&31, row = (reg&3) + 8*(reg>>2) + 4*(lane>>5)
    float* pp = part + (size_t)bid * 16384;
#pragma unroll
    for (int i = 0; i < 2; ++i)
#pragma unroll
        for (int p = 0; p < 16; ++p) {
            int kl = wk * 64 + i * 32 + (p & 3) + 8 * (p >> 2) + 4 * g;
#pragma unroll
            for (int j = 0; j < 2; ++j) {
                int el = we * 64 + j * 32 + l31;
                pp[kl * 128 + el] = acc[i][j][p];
            }
        }
}

// ---------------- K3: reduce partials over 64 chunks, fused colsum, normalize ----------------
__global__ __launch_bounds__(256) void reduce_out(const float* __restrict__ part, const float* __restrict__ psums,
                                                  float* __restrict__ out) {
    int bid = blockIdx.x;
    int ehalf = bid & 1, k = (bid >> 1) & 255, b = bid >> 9;
    int t = threadIdx.x, lane = t & 63;

    float cs = 0.f;
#pragma unroll
    for (int c = 0; c < 4; ++c) {
        int mt = c * 256 + t;
        cs += psums[((size_t)b * 1024 + mt) * 256 + k];
    }
#pragma unroll
    for (int mask = 1; mask < 64; mask <<= 1) cs += __shfl_xor(cs, mask, 64);
    __shared__ float cspart[4];
    if (lane == 0) cspart[t >> 6] = cs;
    __syncthreads();
    float colsum = (cspart[0] + cspart[1]) + (cspart[2] + cspart[3]);

    int e = ehalf * 256 + t;
    int kt = k >> 7, kl = k & 127, et = e >> 7, el = e & 127;
    float s = 0.f;
#pragma unroll
    for (int ch = 0; ch < 64; ++ch) {
        int bid2 = kt | (et << 1) | (ch << 3) | (b << 9);
        s += part[(size_t)bid2 * 16384 + kl * 128 + el];
    }
    out[((size_t)(b * 256 + k)) * 512 + e] = s / colsum;
}

extern "C" void kernel_launch(void* const* d_in, const int* in_sizes, int n_in,
                              void* d_out, int out_size, void* d_ws, size_t ws_size,
                              hipStream_t stream) {
    (void)in_sizes; (void)n_in; (void)out_size; (void)ws_size;
    const float* x = (const float*)d_in[0];
    const float* W = (const float*)d_in[1];
    // d_in[2] (bias) provably cancels in softmax over m -> unused.

    char* ws = (char*)d_ws;
    unsigned char* xT8 = (unsigned char*)ws;               //  67,108,864 B
    bf16_t* Wb    = (bf16_t*)(ws + 67108864);              //     262,144 B
    unsigned char* pb8 = (unsigned char*)(ws + 67371008);  //  33,554,432 B
    float*  psums = (float*)(ws + 100925440);              //   2,097,152 B
    float*  part  = (float*)(ws + 103022592);              //  67,108,864 B (1024 blocks x 16384)
    float*  out   = (float*)d_out;

    cast_w<<<128, 256, 0, stream>>>(W, Wb);
    gemm1_exp_t<<<1024, 512, 0, stream>>>(x, Wb, pb8, psums, xT8);
    gemm2<<<1024, 256, 0, stream>>>(pb8, xT8, part);
    reduce_out<<<1024, 256, 0, stream>>>(part, psums, out);
}

// Round 3
// 490.085 us; speedup vs baseline: 1.3690x; 1.3690x over previous
//
#include <hip/hip_runtime.h>
#include <stdint.h>

#define B_DIM 2
#define M_DIM 65536
#define E_DIM 512
#define K_DIM 256

typedef __bf16 bf16_t;
typedef __bf16 bf16x8 __attribute__((ext_vector_type(8)));
typedef float  f32x4  __attribute__((ext_vector_type(4)));
typedef float  f32x16 __attribute__((ext_vector_type(16)));
typedef int    i32x8  __attribute__((ext_vector_type(8)));

typedef const __attribute__((address_space(1))) void* gas_ptr;
typedef __attribute__((address_space(3))) void* las_ptr;

__device__ __forceinline__ void async_load16(const void* g, void* l) {
    __builtin_amdgcn_global_load_lds((gas_ptr)g, (las_ptr)l, 16, 0, 0);
}

__device__ __forceinline__ unsigned short bf16_bits(float f) {
    return __builtin_bit_cast(unsigned short, (__bf16)f);
}
__device__ __forceinline__ unsigned int pack2(float lo, float hi) {
    return (unsigned int)bf16_bits(lo) | ((unsigned int)bf16_bits(hi) << 16);
}
__device__ __forceinline__ float bf16u_to_f32(unsigned short us) {
    return __builtin_bit_cast(float, (unsigned)us << 16);
}
// pack 8 floats -> 8 fp8 e4m3 bytes (uint2)
__device__ __forceinline__ uint2 pack8_fp8(const float* f) {
    int lo = __builtin_amdgcn_cvt_pk_fp8_f32(f[0], f[1], 0, false);
    lo = __builtin_amdgcn_cvt_pk_fp8_f32(f[2], f[3], lo, true);
    int hi = __builtin_amdgcn_cvt_pk_fp8_f32(f[4], f[5], 0, false);
    hi = __builtin_amdgcn_cvt_pk_fp8_f32(f[6], f[7], hi, true);
    return make_uint2((unsigned)lo, (unsigned)hi);
}

// ---------------- K0: cast W (fp32 -> bf16) ----------------
__global__ __launch_bounds__(256) void cast_w(const float* __restrict__ W, bf16_t* __restrict__ Wb) {
    int idx = blockIdx.x * 256 + threadIdx.x;            // 32768 float4 chunks
    float4 v = ((const float4*)W)[idx];
    ((uint2*)Wb)[idx] = make_uint2(pack2(v.x, v.y), pack2(v.z, v.w));
}

// ---------------- K1: fused GEMM1(bf16) + exp + colsum-partials + fp8 emit of xT, pb ----------------
// BM=128 m-tile, 512 threads = 8 waves (wave w: wk=w>>1 k-quarter, wm=w&1 m-half), BK=64 over e.
// __launch_bounds__(512, 2): cap 256 regs (R2's (512,4) capped at 64 VGPR -> ~570 MB scratch
// spill traffic per dispatch, 329 us). LDS=64KB limits to 2 blocks/CU anyway; with ~160 regs
// we get 1 block/CU (8 waves) and ZERO spill -- the accumulator (64 f32) stays in registers.
__global__ __launch_bounds__(512, 2) void gemm1_exp_t(const float* __restrict__ x, const bf16_t* __restrict__ Wb,
                                                      unsigned char* __restrict__ pb8, float* __restrict__ psums,
                                                      unsigned char* __restrict__ xT8) {
    int gid = blockIdx.x;
    int mt = gid & 511;
    int b  = gid >> 9;
    int m0 = mt * 128;
    int t = threadIdx.x, lane = t & 63, w = t >> 6;
    int wk = w >> 1, wm = w & 1;

    __shared__ __align__(16) char smem[65536];
    bf16_t* Alds = (bf16_t*)smem;              // 256 k-rows x 64 e = 32 KB (K-loop)
    bf16_t* Blds = (bf16_t*)(smem + 32768);    // dbuf: 2 x (128 m-rows x 64 e) = 2 x 16 KB
    bf16_t* Elds = (bf16_t*)smem;              // 256 k x 128 m = 64 KB (epilogue, aliases all)

    const float* xb = x + ((size_t)b * M_DIM + m0) * E_DIM;

    f32x4 zero = {0.f, 0.f, 0.f, 0.f};
    f32x4 acc[4][4];
#pragma unroll
    for (int i = 0; i < 4; ++i)
#pragma unroll
        for (int j = 0; j < 4; ++j) acc[i][j] = zero;

    // B staging: thread t -> m-row r=t>>2 (0..127), LDS slots {t&3, 4+(t&3)}
    int bst_r = t >> 2, bst_s0 = t & 3;
    int ge0 = bst_s0 ^ (bst_r & 7);
    int ge1 = (bst_s0 + 4) ^ (bst_r & 7);

    int q = lane >> 4, r15 = lane & 15;

    // prologue: prefetch x(ke=0) into regs
    float4 xr0, xr1, xr2, xr3;
    {
        const float4* f0 = (const float4*)(xb + (size_t)bst_r * E_DIM + ge0 * 8);
        const float4* f1 = (const float4*)(xb + (size_t)bst_r * E_DIM + ge1 * 8);
        xr0 = f0[0]; xr1 = f0[1];
        xr2 = f1[0]; xr3 = f1[1];
    }

    for (int ke = 0; ke < 8; ++ke) {
        int e0 = ke * 64;
        int cur = ke & 1;
        bf16_t* Bl = Blds + cur * 8192;

        // --- cvt + write x(ke) from regs into idle B buffer (pre-barrier) ---
        *(uint4*)(Bl + bst_r * 64 + bst_s0 * 8) =
            make_uint4(pack2(xr0.x, xr0.y), pack2(xr0.z, xr0.w), pack2(xr1.x, xr1.y), pack2(xr1.z, xr1.w));
        *(uint4*)(Bl + bst_r * 64 + (bst_s0 + 4) * 8) =
            make_uint4(pack2(xr2.x, xr2.y), pack2(xr2.z, xr2.w), pack2(xr3.x, xr3.y), pack2(xr3.z, xr3.w));

        __syncthreads();   // barrier A: prev compute done (Alds free), B-writes visible

        // --- A tile: 256 k-rows x 64 e via global_load_lds (swizzle on global granule) ---
#pragma unroll
        for (int is = 0; is < 4; ++is) {
            int c = is * 512 + t;          // 16B slot id 0..2047, lane-linear LDS dst
            int row = c >> 3, sl = c & 7;
            int ge = sl ^ (row & 7);
            async_load16(Wb + (size_t)row * E_DIM + e0 + ge * 8, Alds + c * 8);
        }
        __syncthreads();   // barrier B: A-DMA drained

        // --- issue x-prefetch for ke+1 (latency hides under compute below) ---
        if (ke < 7) {
            const float4* f0 = (const float4*)(xb + (size_t)bst_r * E_DIM + (e0 + 64) + ge0 * 8);
            const float4* f1 = (const float4*)(xb + (size_t)bst_r * E_DIM + (e0 + 64) + ge1 * 8);
            xr0 = f0[0]; xr1 = f0[1];
            xr2 = f1[0]; xr3 = f1[1];
        }

        // --- compute ---
#pragma unroll
        for (int h = 0; h < 2; ++h) {
            bf16x8 af[4], bfr[4];
#pragma unroll
            for (int i = 0; i < 4; ++i) {
                int r = wk * 64 + i * 16 + r15;
                int sl = (h * 4 + q) ^ (r & 7);
                af[i] = *(const bf16x8*)(Alds + r * 64 + sl * 8);
            }
#pragma unroll
            for (int j = 0; j < 4; ++j) {
                int r = wm * 64 + j * 16 + r15;
                int sl = (h * 4 + q) ^ (r & 7);
                bfr[j] = *(const bf16x8*)(Bl + r * 64 + sl * 8);
            }
#pragma unroll
            for (int i = 0; i < 4; ++i)
#pragma unroll
                for (int j = 0; j < 4; ++j)
                    acc[i][j] = __builtin_amdgcn_mfma_f32_16x16x32_bf16(af[i], bfr[j], acc[i][j], 0, 0, 0);
        }

        // --- xT8 emit: read B-tile columns (rotated m -> conflict-free), cvt to fp8, store ---
        {
            const unsigned short* Bs = (const unsigned short*)Bl;
            int l7 = t & 7;
            int mg = l7 + ((t >> 8) << 3);      // m-granule 0..15
            int mbase = mg * 8;
            int ebase = (t >> 3) & 31;          // 0..31
#pragma unroll
            for (int p = 0; p < 2; ++p) {
                int ecol = p * 32 + ebase;
                float f[8];
#pragma unroll
                for (int s = 0; s < 8; ++s) {
                    int mmr = (s + l7) & 7;     // rotated m&7 -> conflict-free
                    int sl = (ecol >> 3) ^ mmr;
                    f[mmr] = bf16u_to_f32(Bs[(mbase + mmr) * 64 + sl * 8 + (ecol & 7)]);
                }
                *(uint2*)(xT8 + ((size_t)(b * E_DIM + e0 + ecol)) * M_DIM + m0 + mbase) = pack8_fp8(f);
            }
        }
    }
    __syncthreads();   // all compute/emit done before Elds (aliasing) writes

    // ---- epilogue: p = exp(score); per-k partial sums; pb8 via LDS repack ----
    int cc = lane & 15;
    float ksum[4][4];   // [i][p]
#pragma unroll
    for (int i = 0; i < 4; ++i)
#pragma unroll
        for (int p = 0; p < 4; ++p) ksum[i][p] = 0.f;

#pragma unroll
    for (int i = 0; i < 4; ++i) {
        int kr = wk * 64 + i * 16 + q * 4;
#pragma unroll
        for (int j = 0; j < 4; ++j) {
            int colb = wm * 64 + j * 16 + cc;
            int g = colb >> 3, off = colb & 7;
#pragma unroll
            for (int p = 0; p < 4; ++p) {
                float v = __expf(acc[i][j][p]);
                ksum[i][p] += v;
                int k = kr + p;
                Elds[k * 128 + ((g ^ (k & 15)) * 8) + off] = (bf16_t)v;
            }
        }
    }
    // reduce ksum across the 16 cc-lanes of each quad-group (sums this wave's 64-m half)
#pragma unroll
    for (int mask = 1; mask < 16; mask <<= 1)
#pragma unroll
        for (int i = 0; i < 4; ++i)
#pragma unroll
            for (int p = 0; p < 4; ++p)
                ksum[i][p] += __shfl_xor(ksum[i][p], mask, 64);
    if (cc == 0) {
        // psums entry per (m-half): layout [b][1024][256] preserved (mt*2 + wm)
        float* pp = psums + ((size_t)b * 1024 + mt * 2 + wm) * 256;
#pragma unroll
        for (int i = 0; i < 4; ++i)
#pragma unroll
            for (int p = 0; p < 4; ++p)
                pp[wk * 64 + i * 16 + q * 4 + p] = ksum[i][p];
    }
    __syncthreads();

    // cooperative pb8 store: 8 passes, thread covers 16B (bf16 granule pair) of row p*32+(t>>4)
    {
        int g16 = t & 15, rsub = t >> 4;   // rsub 0..31
        unsigned char* dstb = pb8 + (size_t)b * K_DIM * M_DIM + m0;
#pragma unroll
        for (int p = 0; p < 8; ++p) {
            int k = p * 32 + rsub;
            uint4 vv = *(const uint4*)(Elds + k * 128 + ((g16 ^ (k & 15)) * 8));
            const unsigned short* us = (const unsigned short*)&vv;
            float f[8];
#pragma unroll
            for (int s = 0; s < 8; ++s) f[s] = bf16u_to_f32(us[s]);
            *(uint2*)(dstb + (size_t)k * M_DIM + g16 * 8) = pack8_fp8(f);
        }
    }
}

// ---------------- K2: GEMM2 fp8 (MX-scaled, scale=1.0), BK=64 ----------------
// part[bid][kl][el] = sum_m pb[k][m]*xT[e][m]
// block: 128k x 128e, 4 waves (2x2), m-chunk = 1024 (64 chunks -> 1024 blocks, 4/CU), 16 iters.
__global__ __launch_bounds__(256, 4) void gemm2(const unsigned char* __restrict__ pb8, const unsigned char* __restrict__ xT8,
                                                float* __restrict__ part) {
    int bid = blockIdx.x;
    int kt = bid & 1, et = (bid >> 1) & 3, ch = (bid >> 3) & 63, b = bid >> 9;
    int t = threadIdx.x, lane = t & 63, w = t >> 6;
    int wk = w & 1, we = w >> 1;

    __shared__ __align__(16) unsigned char Alds[2][128 * 64];   // 2 x 8 KB
    __shared__ __align__(16) unsigned char Blds[2][128 * 64];   // 2 x 8 KB

    const unsigned char* Ab = pb8 + ((size_t)(b * K_DIM + kt * 128)) * M_DIM + ch * 1024;
    const unsigned char* Bb = xT8 + ((size_t)(b * E_DIM + et * 128)) * M_DIM + ch * 1024;

    f32x16 acc[2][2];
#pragma unroll
    for (int i = 0; i < 2; ++i)
#pragma unroll
        for (int j = 0; j < 2; ++j)
#pragma unroll
            for (int p = 0; p < 16; ++p) acc[i][j][p] = 0.f;

    int l31 = lane & 31, g = lane >> 5;

    auto STAGE = [&](int buf, int m0) {
#pragma unroll
        for (int is = 0; is < 2; ++is) {
            int c = is * 256 + t;          // 16B slot id 0..511, lane-linear LDS dst
            int row = c >> 2, a = c & 3;
            int sr = (row & 3) ^ ((row >> 2) & 3);
            int bsl = a ^ sr;              // phys slot a holds logical slot a^sr
            async_load16(Ab + (size_t)row * M_DIM + m0 + bsl * 16, &Alds[buf][c * 16]);
            async_load16(Bb + (size_t)row * M_DIM + m0 + bsl * 16, &Blds[buf][c * 16]);
        }
    };

    STAGE(0, 0);
    __syncthreads();                       // drain prologue staging

    for (int km = 0; km < 16; ++km) {
        int cur = km & 1;
        if (km + 1 < 16) STAGE(cur ^ 1, (km + 1) * 64);   // issue next tile early

        i32x8 av[2], bv[2];
#pragma unroll
        for (int i = 0; i < 2; ++i) {
            int r = wk * 64 + i * 32 + l31;
            int sr = (r & 3) ^ ((r >> 2) & 3);
            int4 lo = *(const int4*)(&Alds[cur][r * 64 + (((2 * g) ^ sr) * 16)]);
            int4 hi = *(const int4*)(&Alds[cur][r * 64 + (((2 * g + 1) ^ sr) * 16)]);
            av[i][0] = lo.x; av[i][1] = lo.y; av[i][2] = lo.z; av[i][3] = lo.w;
            av[i][4] = hi.x; av[i][5] = hi.y; av[i][6] = hi.z; av[i][7] = hi.w;
        }
#pragma unroll
        for (int j = 0; j < 2; ++j) {
            int r = we * 64 + j * 32 + l31;
            int sr = (r & 3) ^ ((r >> 2) & 3);
            int4 lo = *(const int4*)(&Blds[cur][r * 64 + (((2 * g) ^ sr) * 16)]);
            int4 hi = *(const int4*)(&Blds[cur][r * 64 + (((2 * g + 1) ^ sr) * 16)]);
            bv[j][0] = lo.x; bv[j][1] = lo.y; bv[j][2] = lo.z; bv[j][3] = lo.w;
            bv[j][4] = hi.x; bv[j][5] = hi.y; bv[j][6] = hi.z; bv[j][7] = hi.w;
        }

        __builtin_amdgcn_s_setprio(1);
#pragma unroll
        for (int i = 0; i < 2; ++i)
#pragma unroll
            for (int j = 0; j < 2; ++j)
                acc[i][j] = __builtin_amdgcn_mfma_scale_f32_32x32x64_f8f6f4(
                    av[i], bv[j], acc[i][j],
                    0 /*cbsz: fp8 e4m3*/, 0 /*blgp: fp8 e4m3*/,
                    0, 0x7f7f7f7f /*scale A = 1.0*/,
                    0, 0x7f7f7f7f /*scale B = 1.0*/);
        __builtin_amdgcn_s_setprio(0);

        __syncthreads();   // waves done reading buf[cur]; next-tile staging drained
    }

    // C/D 32x32 layout: col = lane&31, row = (reg&3) + 8*(reg>>2) + 4*(lane>>5)
    float* pp = part + (size_t)bid * 16384;
#pragma unroll
    for (int i = 0; i < 2; ++i)
#pragma unroll
        for (int p = 0; p < 16; ++p) {
            int kl = wk * 64 + i * 32 + (p & 3) + 8 * (p >> 2) + 4 * g;
#pragma unroll
            for (int j = 0; j < 2; ++j) {
                int el = we * 64 + j * 32 + l31;
                pp[kl * 128 + el] = acc[i][j][p];
            }
        }
}

// ---------------- K3: reduce partials over 64 chunks, fused colsum, normalize ----------------
__global__ __launch_bounds__(256) void reduce_out(const float* __restrict__ part, const float* __restrict__ psums,
                                                  float* __restrict__ out) {
    int bid = blockIdx.x;
    int ehalf = bid & 1, k = (bid >> 1) & 255, b = bid >> 9;
    int t = threadIdx.x, lane = t & 63;

    float cs = 0.f;
#pragma unroll
    for (int c = 0; c < 4; ++c) {
        int mt = c * 256 + t;
        cs += psums[((size_t)b * 1024 + mt) * 256 + k];
    }
#pragma unroll
    for (int mask = 1; mask < 64; mask <<= 1) cs += __shfl_xor(cs, mask, 64);
    __shared__ float cspart[4];
    if (lane == 0) cspart[t >> 6] = cs;
    __syncthreads();
    float colsum = (cspart[0] + cspart[1]) + (cspart[2] + cspart[3]);

    int e = ehalf * 256 + t;
    int kt = k >> 7, kl = k & 127, et = e >> 7, el = e & 127;
    float s = 0.f;
#pragma unroll
    for (int ch = 0; ch < 64; ++ch) {
        int bid2 = kt | (et << 1) | (ch << 3) | (b << 9);
        s += part[(size_t)bid2 * 16384 + kl * 128 + el];
    }
    out[((size_t)(b * 256 + k)) * 512 + e] = s / colsum;
}

extern "C" void kernel_launch(void* const* d_in, const int* in_sizes, int n_in,
                              void* d_out, int out_size, void* d_ws, size_t ws_size,
                              hipStream_t stream) {
    (void)in_sizes; (void)n_in; (void)out_size; (void)ws_size;
    const float* x = (const float*)d_in[0];
    const float* W = (const float*)d_in[1];
    // d_in[2] (bias) provably cancels in softmax over m -> unused.

    char* ws = (char*)d_ws;
    unsigned char* xT8 = (unsigned char*)ws;               //  67,108,864 B
    bf16_t* Wb    = (bf16_t*)(ws + 67108864);              //     262,144 B
    unsigned char* pb8 = (unsigned char*)(ws + 67371008);  //  33,554,432 B
    float*  psums = (float*)(ws + 100925440);              //   2,097,152 B
    float*  part  = (float*)(ws + 103022592);              //  67,108,864 B (1024 blocks x 16384)
    float*  out   = (float*)d_out;

    cast_w<<<128, 256, 0, stream>>>(W, Wb);
    gemm1_exp_t<<<1024, 512, 0, stream>>>(x, Wb, pb8, psums, xT8);
    gemm2<<<1024, 256, 0, stream>>>(pb8, xT8, part);
    reduce_out<<<1024, 256, 0, stream>>>(part, psums, out);
}

// Round 4
// 435.999 us; speedup vs baseline: 1.5388x; 1.1241x over previous
//
#include <hip/hip_runtime.h>
#include <stdint.h>

#define B_DIM 2
#define M_DIM 65536
#define E_DIM 512
#define K_DIM 256

typedef __bf16 bf16_t;
typedef __bf16 bf16x8 __attribute__((ext_vector_type(8)));
typedef float  f32x4  __attribute__((ext_vector_type(4)));
typedef float  f32x16 __attribute__((ext_vector_type(16)));
typedef int    i32x8  __attribute__((ext_vector_type(8)));

typedef const __attribute__((address_space(1))) void* gas_ptr;
typedef __attribute__((address_space(3))) void* las_ptr;

__device__ __forceinline__ void async_load16(const void* g, void* l) {
    __builtin_amdgcn_global_load_lds((gas_ptr)g, (las_ptr)l, 16, 0, 0);
}

__device__ __forceinline__ unsigned short bf16_bits(float f) {
    return __builtin_bit_cast(unsigned short, (__bf16)f);
}
__device__ __forceinline__ unsigned int pack2(float lo, float hi) {
    return (unsigned int)bf16_bits(lo) | ((unsigned int)bf16_bits(hi) << 16);
}
__device__ __forceinline__ float bf16u_to_f32(unsigned short us) {
    return __builtin_bit_cast(float, (unsigned)us << 16);
}
// pack 8 floats -> 8 fp8 e4m3 bytes (uint2)
__device__ __forceinline__ uint2 pack8_fp8(const float* f) {
    int lo = __builtin_amdgcn_cvt_pk_fp8_f32(f[0], f[1], 0, false);
    lo = __builtin_amdgcn_cvt_pk_fp8_f32(f[2], f[3], lo, true);
    int hi = __builtin_amdgcn_cvt_pk_fp8_f32(f[4], f[5], 0, false);
    hi = __builtin_amdgcn_cvt_pk_fp8_f32(f[6], f[7], hi, true);
    return make_uint2((unsigned)lo, (unsigned)hi);
}

// ---------------- K0: cast W (fp32 -> bf16) ----------------
__global__ __launch_bounds__(256) void cast_w(const float* __restrict__ W, bf16_t* __restrict__ Wb) {
    int idx = blockIdx.x * 256 + threadIdx.x;            // 32768 float4 chunks
    float4 v = ((const float4*)W)[idx];
    ((uint2*)Wb)[idx] = make_uint2(pack2(v.x, v.y), pack2(v.z, v.w));
}

// ---------------- K1: fused GEMM1(bf16) + exp + colsum-partials + fp8 emit of xT, pb ----------------
// R1-proven shell: block 256k x 64m, 4 waves, BK=64, 40KB LDS (~4 blocks/CU TLP).
// Only change vs R1: psums written TRANSPOSED [b][k][mt] so reduce_out's gather coalesces.
__global__ __launch_bounds__(256) void gemm1_exp_t(const float* __restrict__ x, const bf16_t* __restrict__ Wb,
                                                   unsigned char* __restrict__ pb8, float* __restrict__ psums,
                                                   unsigned char* __restrict__ xT8) {
    int gid = blockIdx.x;
    int mt = gid & 1023;
    int b  = gid >> 10;
    int m0 = mt * 64;
    int t = threadIdx.x, lane = t & 63, w = t >> 6;

    __shared__ __align__(16) char smem[40960];
    bf16_t* Alds = (bf16_t*)smem;              // 256 k-rows x 64 e = 32 KB (K-loop)
    bf16_t* Blds = (bf16_t*)(smem + 32768);    //  64 m-rows x 64 e =  8 KB (K-loop)
    bf16_t* Elds = (bf16_t*)smem;              // 256 k x 64 m = 32 KB (epilogue, aliases Alds)

    const float* xb = x + ((size_t)b * M_DIM + m0) * E_DIM;

    f32x4 zero = {0.f, 0.f, 0.f, 0.f};
    f32x4 acc[4][4];
#pragma unroll
    for (int i = 0; i < 4; ++i)
#pragma unroll
        for (int j = 0; j < 4; ++j) acc[i][j] = zero;

    // B staging: thread t -> m-row r=t>>2, LDS slots {t&3, 4+(t&3)}
    int bst_r = t >> 2, bst_s0 = t & 3;

    int q = lane >> 4, r15 = lane & 15;

    for (int ke = 0; ke < 8; ++ke) {
        int e0 = ke * 64;
        // --- A tile: 256 k-rows x 64 e via global_load_lds (swizzle on global granule) ---
#pragma unroll
        for (int is = 0; is < 8; ++is) {
            int c = is * 256 + t;          // 16B slot id, lane-linear LDS dst
            int row = c >> 3, sl = c & 7;
            int ge = sl ^ (row & 7);
            async_load16(Wb + (size_t)row * E_DIM + e0 + ge * 8, Alds + c * 8);
        }
        // --- B tile: 64 m-rows x 64 e fp32 -> bf16 (2 granules/thread) ---
#pragma unroll
        for (int sg = 0; sg < 2; ++sg) {
            int sl = bst_s0 + sg * 4;
            int ge = sl ^ (bst_r & 7);
            const float4* f = (const float4*)(xb + (size_t)bst_r * E_DIM + e0 + ge * 8);
            float4 a0 = f[0], a1 = f[1];
            *(uint4*)(Blds + bst_r * 64 + sl * 8) =
                make_uint4(pack2(a0.x, a0.y), pack2(a0.z, a0.w), pack2(a1.x, a1.y), pack2(a1.z, a1.w));
        }
        __syncthreads();

#pragma unroll
        for (int h = 0; h < 2; ++h) {
            bf16x8 af[4], bfr[4];
#pragma unroll
            for (int i = 0; i < 4; ++i) {
                int r = w * 64 + i * 16 + r15;
                int sl = (h * 4 + q) ^ (r & 7);
                af[i] = *(const bf16x8*)(Alds + r * 64 + sl * 8);
            }
#pragma unroll
            for (int j = 0; j < 4; ++j) {
                int r = j * 16 + r15;
                int sl = (h * 4 + q) ^ (r & 7);
                bfr[j] = *(const bf16x8*)(Blds + r * 64 + sl * 8);
            }
#pragma unroll
            for (int i = 0; i < 4; ++i)
#pragma unroll
                for (int j = 0; j < 4; ++j)
                    acc[i][j] = __builtin_amdgcn_mfma_f32_16x16x32_bf16(af[i], bfr[j], acc[i][j], 0, 0, 0);
        }

        // --- xT8 emit: read B-tile columns (rotated m -> conflict-free), cvt to fp8, store ---
        {
            const unsigned short* Bs = (const unsigned short*)Blds;
            int l7 = t & 7;
            int mbase = l7 * 8;
            int ebase = t >> 3;                 // 0..31
#pragma unroll
            for (int p = 0; p < 2; ++p) {
                int ecol = p * 32 + ebase;
                float f[8];
#pragma unroll
                for (int s = 0; s < 8; ++s) {
                    int mmr = (s + l7) & 7;     // rotated m&7 -> conflict-free
                    int sl = (ecol >> 3) ^ mmr;
                    f[mmr] = bf16u_to_f32(Bs[(mbase + mmr) * 64 + sl * 8 + (ecol & 7)]);
                }
                *(uint2*)(xT8 + ((size_t)(b * E_DIM + e0 + ecol)) * M_DIM + m0 + mbase) = pack8_fp8(f);
            }
        }
        __syncthreads();
    }

    // ---- epilogue: p = exp(score); per-k partial sums; pb8 via LDS repack ----
    int cc = lane & 15;
    float ksum[4][4];   // [i][p]
#pragma unroll
    for (int i = 0; i < 4; ++i)
#pragma unroll
        for (int p = 0; p < 4; ++p) ksum[i][p] = 0.f;

#pragma unroll
    for (int i = 0; i < 4; ++i) {
        int kr = w * 64 + i * 16 + q * 4;
#pragma unroll
        for (int j = 0; j < 4; ++j) {
            int colb = j * 16 + cc;
            int g = colb >> 3, off = colb & 7;
#pragma unroll
            for (int p = 0; p < 4; ++p) {
                float v = __expf(acc[i][j][p]);
                ksum[i][p] += v;
                int k = kr + p;
                Elds[k * 64 + ((g ^ (k & 7)) * 8) + off] = (bf16_t)v;
            }
        }
    }
    // reduce ksum across the 16 cc-lanes of each quad-group
#pragma unroll
    for (int mask = 1; mask < 16; mask <<= 1)
#pragma unroll
        for (int i = 0; i < 4; ++i)
#pragma unroll
            for (int p = 0; p < 4; ++p)
                ksum[i][p] += __shfl_xor(ksum[i][p], mask, 64);
    if (cc == 0) {
        // TRANSPOSED psums: [b][k][mt]  (reduce_out gathers mt contiguously)
        float* pp = psums + (size_t)b * K_DIM * 1024 + mt;
#pragma unroll
        for (int i = 0; i < 4; ++i)
#pragma unroll
            for (int p = 0; p < 4; ++p)
                pp[(size_t)(w * 64 + i * 16 + q * 4 + p) * 1024] = ksum[i][p];
    }
    __syncthreads();

    // cooperative pb8 store: 8 passes, lanes t&7 cover 64B (fp8) of row p*32+(t>>3)
    {
        int g = t & 7, rsub = t >> 3;
        unsigned char* dstb = pb8 + (size_t)b * K_DIM * M_DIM + m0;
#pragma unroll
        for (int p = 0; p < 8; ++p) {
            int k = p * 32 + rsub;
            const unsigned short* src = (const unsigned short*)(Elds + k * 64 + ((g ^ (k & 7)) * 8));
            float f[8];
#pragma unroll
            for (int s = 0; s < 8; ++s) f[s] = bf16u_to_f32(src[s]);
            *(uint2*)(dstb + (size_t)k * M_DIM + g * 8) = pack8_fp8(f);
        }
    }
}

// ---------------- K2: GEMM2 fp8 (MX-scaled, scale=1.0), BK=64 ----------------
// part[logical_bid][kl][el] = sum_m pb[k][m]*xT[e][m]
// R1-exact structure (512 blocks, 128k x 128e, m-chunk 2048, dbuf, 32 iters) with ONE change:
// XCD-GROUP REMAP. Logical fields (kt,et,ch,b): the 8 blocks {kt}x{et} sharing one m-window
// re-fetch the same pb8 columns (4x) and xT8 columns (2x). Old bid = kt|et<<1|ch<<3|b<<8 put
// those 8 on 8 DIFFERENT XCDs (bid%8 round-robin) -> 8 private-L2 copies, ~268 MB fabric/HBM.
// New phys id p = xcd + 8*(kt_et + 8*cb) puts all 8 on ONE XCD (same p%8) -> 1 fetch + 7 L2
// hits; window working set 512 KB << 4 MB L2. part[] stays indexed by LOGICAL bid, so
// reduce_out is unchanged.
__global__ __launch_bounds__(256) void gemm2(const unsigned char* __restrict__ pb8, const unsigned char* __restrict__ xT8,
                                             float* __restrict__ part) {
    int p_ = blockIdx.x;
    int xcd = p_ & 7, idx = p_ >> 3;
    int kt_et = idx & 7, cb = idx >> 3;          // cb 0..7
    int kt = kt_et & 1, et = kt_et >> 1;
    int c2 = (cb << 3) | xcd;                    // 0..63
    int ch = c2 & 31, b = c2 >> 5;
    int lbid = kt | (et << 1) | (ch << 3) | (b << 8);   // logical bid for part[]

    int t = threadIdx.x, lane = t & 63, w = t >> 6;
    int wk = w & 1, we = w >> 1;

    __shared__ __align__(16) unsigned char Alds[2][128 * 64];   // 2 x 8 KB
    __shared__ __align__(16) unsigned char Blds[2][128 * 64];   // 2 x 8 KB

    const unsigned char* Ab = pb8 + ((size_t)(b * K_DIM + kt * 128)) * M_DIM + ch * 2048;
    const unsigned char* Bb = xT8 + ((size_t)(b * E_DIM + et * 128)) * M_DIM + ch * 2048;

    f32x16 acc[2][2];
#pragma unroll
    for (int i = 0; i < 2; ++i)
#pragma unroll
        for (int j = 0; j < 2; ++j)
#pragma unroll
            for (int p = 0; p < 16; ++p) acc[i][j][p] = 0.f;

    int l31 = lane & 31, g = lane >> 5;

    auto STAGE = [&](int buf, int m0) {
#pragma unroll
        for (int is = 0; is < 2; ++is) {
            int c = is * 256 + t;          // 16B slot id 0..511, lane-linear LDS dst
            int row = c >> 2, a = c & 3;
            int sr = (row & 3) ^ ((row >> 2) & 3);
            int bsl = a ^ sr;              // phys slot a holds logical slot a^sr
            async_load16(Ab + (size_t)row * M_DIM + m0 + bsl * 16, &Alds[buf][c * 16]);
            async_load16(Bb + (size_t)row * M_DIM + m0 + bsl * 16, &Blds[buf][c * 16]);
        }
    };

    STAGE(0, 0);
    __syncthreads();                       // drain prologue staging

    for (int km = 0; km < 32; ++km) {
        int cur = km & 1;
        if (km + 1 < 32) STAGE(cur ^ 1, (km + 1) * 64);   // issue next tile early

        i32x8 av[2], bv[2];
#pragma unroll
        for (int i = 0; i < 2; ++i) {
            int r = wk * 64 + i * 32 + l31;
            int sr = (r & 3) ^ ((r >> 2) & 3);
            int4 lo = *(const int4*)(&Alds[cur][r * 64 + (((2 * g) ^ sr) * 16)]);
            int4 hi = *(const int4*)(&Alds[cur][r * 64 + (((2 * g + 1) ^ sr) * 16)]);
            av[i][0] = lo.x; av[i][1] = lo.y; av[i][2] = lo.z; av[i][3] = lo.w;
            av[i][4] = hi.x; av[i][5] = hi.y; av[i][6] = hi.z; av[i][7] = hi.w;
        }
#pragma unroll
        for (int j = 0; j < 2; ++j) {
            int r = we * 64 + j * 32 + l31;
            int sr = (r & 3) ^ ((r >> 2) & 3);
            int4 lo = *(const int4*)(&Blds[cur][r * 64 + (((2 * g) ^ sr) * 16)]);
            int4 hi = *(const int4*)(&Blds[cur][r * 64 + (((2 * g + 1) ^ sr) * 16)]);
            bv[j][0] = lo.x; bv[j][1] = lo.y; bv[j][2] = lo.z; bv[j][3] = lo.w;
            bv[j][4] = hi.x; bv[j][5] = hi.y; bv[j][6] = hi.z; bv[j][7] = hi.w;
        }

        __builtin_amdgcn_s_setprio(1);
#pragma unroll
        for (int i = 0; i < 2; ++i)
#pragma unroll
            for (int j = 0; j < 2; ++j)
                acc[i][j] = __builtin_amdgcn_mfma_scale_f32_32x32x64_f8f6f4(
                    av[i], bv[j], acc[i][j],
                    0 /*cbsz: fp8 e4m3*/, 0 /*blgp: fp8 e4m3*/,
                    0, 0x7f7f7f7f /*scale A = 1.0*/,
                    0, 0x7f7f7f7f /*scale B = 1.0*/);
        __builtin_amdgcn_s_setprio(0);

        __syncthreads();   // waves done reading buf[cur]; next-tile staging drained
    }

    // C/D 32x32 layout: col = lane&31, row = (reg&3) + 8*(reg>>2) + 4*(lane>>5)
    float* pp = part + (size_t)lbid * 16384;
#pragma unroll
    for (int i = 0; i < 2; ++i)
#pragma unroll
        for (int p = 0; p < 16; ++p) {
            int kl = wk * 64 + i * 32 + (p & 3) + 8 * (p >> 2) + 4 * g;
#pragma unroll
            for (int j = 0; j < 2; ++j) {
                int el = we * 64 + j * 32 + l31;
                pp[kl * 128 + el] = acc[i][j][p];
            }
        }
}

// ---------------- K3: reduce partials over 32 chunks, fused colsum, normalize ----------------
// psums now TRANSPOSED [b][k][mt] -> the colsum gather is fully coalesced (contiguous mt).
__global__ __launch_bounds__(256) void reduce_out(const float* __restrict__ part, const float* __restrict__ psums,
                                                  float* __restrict__ out) {
    int bid = blockIdx.x;
    int ehalf = bid & 1, k = (bid >> 1) & 255, b = bid >> 9;
    int t = threadIdx.x, lane = t & 63;

    const float* ps = psums + (size_t)b * K_DIM * 1024 + (size_t)k * 1024;
    float cs = 0.f;
#pragma unroll
    for (int c = 0; c < 4; ++c) cs += ps[c * 256 + t];
#pragma unroll
    for (int mask = 1; mask < 64; mask <<= 1) cs += __shfl_xor(cs, mask, 64);
    __shared__ float cspart[4];
    if (lane == 0) cspart[t >> 6] = cs;
    __syncthreads();
    float colsum = (cspart[0] + cspart[1]) + (cspart[2] + cspart[3]);

    int e = ehalf * 256 + t;
    int kt = k >> 7, kl = k & 127, et = e >> 7, el = e & 127;
    float s = 0.f;
#pragma unroll
    for (int ch = 0; ch < 32; ++ch) {
        int bid2 = kt | (et << 1) | (ch << 3) | (b << 8);
        s += part[(size_t)bid2 * 16384 + kl * 128 + el];
    }
    out[((size_t)(b * 256 + k)) * 512 + e] = s / colsum;
}

extern "C" void kernel_launch(void* const* d_in, const int* in_sizes, int n_in,
                              void* d_out, int out_size, void* d_ws, size_t ws_size,
                              hipStream_t stream) {
    (void)in_sizes; (void)n_in; (void)out_size; (void)ws_size;
    const float* x = (const float*)d_in[0];
    const float* W = (const float*)d_in[1];
    // d_in[2] (bias) provably cancels in softmax over m -> unused.

    char* ws = (char*)d_ws;
    unsigned char* xT8 = (unsigned char*)ws;               //  67,108,864 B
    bf16_t* Wb    = (bf16_t*)(ws + 67108864);              //     262,144 B
    unsigned char* pb8 = (unsigned char*)(ws + 67371008);  //  33,554,432 B
    float*  psums = (float*)(ws + 100925440);              //   2,097,152 B  [b][k][mt]
    float*  part  = (float*)(ws + 103022592);              //  33,554,432 B (512 logical bids x 16384)
    float*  out   = (float*)d_out;

    cast_w<<<128, 256, 0, stream>>>(W, Wb);
    gemm1_exp_t<<<2048, 256, 0, stream>>>(x, Wb, pb8, psums, xT8);
    gemm2<<<512, 256, 0, stream>>>(pb8, xT8, part);
    reduce_out<<<1024, 256, 0, stream>>>(part, psums, out);
}

// Round 5
// 434.471 us; speedup vs baseline: 1.5442x; 1.0035x over previous
//
#include <hip/hip_runtime.h>
#include <stdint.h>

#define B_DIM 2
#define M_DIM 65536
#define E_DIM 512
#define K_DIM 256

typedef __bf16 bf16_t;
typedef __bf16 bf16x8 __attribute__((ext_vector_type(8)));
typedef float  f32x4  __attribute__((ext_vector_type(4)));
typedef float  f32x16 __attribute__((ext_vector_type(16)));
typedef int    i32x8  __attribute__((ext_vector_type(8)));

typedef const __attribute__((address_space(1))) void* gas_ptr;
typedef __attribute__((address_space(3))) void* las_ptr;

__device__ __forceinline__ void async_load16(const void* g, void* l) {
    __builtin_amdgcn_global_load_lds((gas_ptr)g, (las_ptr)l, 16, 0, 0);
}

__device__ __forceinline__ unsigned short bf16_bits(float f) {
    return __builtin_bit_cast(unsigned short, (__bf16)f);
}
__device__ __forceinline__ unsigned int pack2(float lo, float hi) {
    return (unsigned int)bf16_bits(lo) | ((unsigned int)bf16_bits(hi) << 16);
}
__device__ __forceinline__ float bf16u_to_f32(unsigned short us) {
    return __builtin_bit_cast(float, (unsigned)us << 16);
}
// pack 8 floats -> 8 fp8 e4m3 bytes (uint2)
__device__ __forceinline__ uint2 pack8_fp8(const float* f) {
    int lo = __builtin_amdgcn_cvt_pk_fp8_f32(f[0], f[1], 0, false);
    lo = __builtin_amdgcn_cvt_pk_fp8_f32(f[2], f[3], lo, true);
    int hi = __builtin_amdgcn_cvt_pk_fp8_f32(f[4], f[5], 0, false);
    hi = __builtin_amdgcn_cvt_pk_fp8_f32(f[6], f[7], hi, true);
    return make_uint2((unsigned)lo, (unsigned)hi);
}

// ---------------- K0: cast W (fp32 -> bf16) ----------------
__global__ __launch_bounds__(256) void cast_w(const float* __restrict__ W, bf16_t* __restrict__ Wb) {
    int idx = blockIdx.x * 256 + threadIdx.x;            // 32768 float4 chunks
    float4 v = ((const float4*)W)[idx];
    ((uint2*)Wb)[idx] = make_uint2(pack2(v.x, v.y), pack2(v.z, v.w));
}

// ---------------- K1: fused GEMM1(bf16) + exp + colsum-partials + fp8 emit of xT, pb ----------------
// R1 shell (256 threads, 4 waves, BM=64, BK=64) with a SOFTWARE-PIPELINED K-loop:
// A-tile AND B-tile double-buffered (80 KB LDS, 2 blocks/CU). Per iter:
//   pack x(ke)->B[cur]  ->  __syncthreads()  [drains A-DMA(ke), which has been in flight
//   under the ENTIRE previous compute phase -> cheap]  ->  issue A-DMA(ke+1) -> issue
//   x-loads(ke+1) -> MFMA+emit on A[cur]/B[cur].
// One barrier/iter; every load is issued a full compute phase before its consumer.
// (R1 issued the A-DMA immediately before the consuming barrier: full latency exposed 8x.)
__global__ __launch_bounds__(256, 2) void gemm1_exp_t(const float* __restrict__ x, const bf16_t* __restrict__ Wb,
                                                      unsigned char* __restrict__ pb8, float* __restrict__ psums,
                                                      unsigned char* __restrict__ xT8) {
    int gid = blockIdx.x;
    int mt = gid & 1023;
    int b  = gid >> 10;
    int m0 = mt * 64;
    int t = threadIdx.x, lane = t & 63, w = t >> 6;

    __shared__ __align__(16) char smem[81920];
    // A dbuf: 2 x (256 k-rows x 64 e bf16) = 2 x 32 KB at offset 0
    // B dbuf: 2 x ( 64 m-rows x 64 e bf16) = 2 x  8 KB at offset 65536
    bf16_t* Elds = (bf16_t*)smem;              // epilogue: 256 k x 64 m = 32 KB (aliases A[0])

    const float* xb = x + ((size_t)b * M_DIM + m0) * E_DIM;

    f32x4 zero = {0.f, 0.f, 0.f, 0.f};
    f32x4 acc[4][4];
#pragma unroll
    for (int i = 0; i < 4; ++i)
#pragma unroll
        for (int j = 0; j < 4; ++j) acc[i][j] = zero;

    // B staging: thread t -> m-row r=t>>2, LDS slots {t&3, 4+(t&3)}
    int bst_r = t >> 2, bst_s0 = t & 3;
    int ge0 = bst_s0 ^ (bst_r & 7);
    int ge1 = (bst_s0 + 4) ^ (bst_r & 7);

    int q = lane >> 4, r15 = lane & 15;

    // ---- prologue: x(0) -> regs; issue A-DMA(0) into A[0] ----
    float4 xr0, xr1, xr2, xr3;
    {
        const float4* f0 = (const float4*)(xb + (size_t)bst_r * E_DIM + ge0 * 8);
        const float4* f1 = (const float4*)(xb + (size_t)bst_r * E_DIM + ge1 * 8);
        xr0 = f0[0]; xr1 = f0[1];
        xr2 = f1[0]; xr3 = f1[1];
    }
    {
        bf16_t* Al = (bf16_t*)smem;            // A[0]
#pragma unroll
        for (int is = 0; is < 8; ++is) {
            int c = is * 256 + t;              // 16B slot id, lane-linear LDS dst
            int row = c >> 3, sl = c & 7;
            int ge = sl ^ (row & 7);
            async_load16(Wb + (size_t)row * E_DIM + 0 + ge * 8, Al + c * 8);
        }
    }

    for (int ke = 0; ke < 8; ++ke) {
        int e0 = ke * 64;
        int cur = ke & 1;
        bf16_t* Al = (bf16_t*)(smem + cur * 32768);
        bf16_t* Bl = (bf16_t*)(smem + 65536 + cur * 8192);

        // --- pack x(ke) from regs -> B[cur] (pre-barrier) ---
        *(uint4*)(Bl + bst_r * 64 + bst_s0 * 8) =
            make_uint4(pack2(xr0.x, xr0.y), pack2(xr0.z, xr0.w), pack2(xr1.x, xr1.y), pack2(xr1.z, xr1.w));
        *(uint4*)(Bl + bst_r * 64 + (bst_s0 + 4) * 8) =
            make_uint4(pack2(xr2.x, xr2.y), pack2(xr2.z, xr2.w), pack2(xr3.x, xr3.y), pack2(xr3.z, xr3.w));

        __syncthreads();   // drains A-DMA(ke) (in flight since prev iter); B[cur] visible

        // --- issue A-DMA(ke+1) into A[cur^1]; safe: all waves finished reading A[cur^1] ---
        if (ke < 7) {
            bf16_t* An = (bf16_t*)(smem + (cur ^ 1) * 32768);
#pragma unroll
            for (int is = 0; is < 8; ++is) {
                int c = is * 256 + t;
                int row = c >> 3, sl = c & 7;
                int ge = sl ^ (row & 7);
                async_load16(Wb + (size_t)row * E_DIM + (e0 + 64) + ge * 8, An + c * 8);
            }
            // --- issue x-loads(ke+1) -> regs (consumed at next iter's pack) ---
            const float4* f0 = (const float4*)(xb + (size_t)bst_r * E_DIM + (e0 + 64) + ge0 * 8);
            const float4* f1 = (const float4*)(xb + (size_t)bst_r * E_DIM + (e0 + 64) + ge1 * 8);
            xr0 = f0[0]; xr1 = f0[1];
            xr2 = f1[0]; xr3 = f1[1];
        }

        // --- compute on A[cur]/B[cur] ---
#pragma unroll
        for (int h = 0; h < 2; ++h) {
            bf16x8 af[4], bfr[4];
#pragma unroll
            for (int i = 0; i < 4; ++i) {
                int r = w * 64 + i * 16 + r15;
                int sl = (h * 4 + q) ^ (r & 7);
                af[i] = *(const bf16x8*)(Al + r * 64 + sl * 8);
            }
#pragma unroll
            for (int j = 0; j < 4; ++j) {
                int r = j * 16 + r15;
                int sl = (h * 4 + q) ^ (r & 7);
                bfr[j] = *(const bf16x8*)(Bl + r * 64 + sl * 8);
            }
#pragma unroll
            for (int i = 0; i < 4; ++i)
#pragma unroll
                for (int j = 0; j < 4; ++j)
                    acc[i][j] = __builtin_amdgcn_mfma_f32_16x16x32_bf16(af[i], bfr[j], acc[i][j], 0, 0, 0);
        }

        // --- xT8 emit: read B[cur] columns (rotated m -> conflict-free), cvt to fp8, store ---
        {
            const unsigned short* Bs = (const unsigned short*)Bl;
            int l7 = t & 7;
            int mbase = l7 * 8;
            int ebase = t >> 3;                 // 0..31
#pragma unroll
            for (int p = 0; p < 2; ++p) {
                int ecol = p * 32 + ebase;
                float f[8];
#pragma unroll
                for (int s = 0; s < 8; ++s) {
                    int mmr = (s + l7) & 7;     // rotated m&7 -> conflict-free
                    int sl = (ecol >> 3) ^ mmr;
                    f[mmr] = bf16u_to_f32(Bs[(mbase + mmr) * 64 + sl * 8 + (ecol & 7)]);
                }
                *(uint2*)(xT8 + ((size_t)(b * E_DIM + e0 + ecol)) * M_DIM + m0 + mbase) = pack8_fp8(f);
            }
        }
        // no second barrier: next iter's B[cur^1] pack and A-DMA targets are only touched
        // after the next __syncthreads(); Elds epilogue writes (A[0] region) are disjoint
        // from the last iteration's A[1]/B[1] reads.
    }

    // ---- epilogue: p = exp(score); per-k partial sums; pb8 via LDS repack ----
    int cc = lane & 15;
    float ksum[4][4];   // [i][p]
#pragma unroll
    for (int i = 0; i < 4; ++i)
#pragma unroll
        for (int p = 0; p < 4; ++p) ksum[i][p] = 0.f;

#pragma unroll
    for (int i = 0; i < 4; ++i) {
        int kr = w * 64 + i * 16 + q * 4;
#pragma unroll
        for (int j = 0; j < 4; ++j) {
            int colb = j * 16 + cc;
            int g = colb >> 3, off = colb & 7;
#pragma unroll
            for (int p = 0; p < 4; ++p) {
                float v = __expf(acc[i][j][p]);
                ksum[i][p] += v;
                int k = kr + p;
                Elds[k * 64 + ((g ^ (k & 7)) * 8) + off] = (bf16_t)v;
            }
        }
    }
    // reduce ksum across the 16 cc-lanes of each quad-group
#pragma unroll
    for (int mask = 1; mask < 16; mask <<= 1)
#pragma unroll
        for (int i = 0; i < 4; ++i)
#pragma unroll
            for (int p = 0; p < 4; ++p)
                ksum[i][p] += __shfl_xor(ksum[i][p], mask, 64);
    if (cc == 0) {
        // TRANSPOSED psums: [b][k][mt]  (reduce_out gathers mt contiguously)
        float* pp = psums + (size_t)b * K_DIM * 1024 + mt;
#pragma unroll
        for (int i = 0; i < 4; ++i)
#pragma unroll
            for (int p = 0; p < 4; ++p)
                pp[(size_t)(w * 64 + i * 16 + q * 4 + p) * 1024] = ksum[i][p];
    }
    __syncthreads();

    // cooperative pb8 store: 8 passes, lanes t&7 cover 64B (fp8) of row p*32+(t>>3)
    {
        int g = t & 7, rsub = t >> 3;
        unsigned char* dstb = pb8 + (size_t)b * K_DIM * M_DIM + m0;
#pragma unroll
        for (int p = 0; p < 8; ++p) {
            int k = p * 32 + rsub;
            const unsigned short* src = (const unsigned short*)(Elds + k * 64 + ((g ^ (k & 7)) * 8));
            float f[8];
#pragma unroll
            for (int s = 0; s < 8; ++s) f[s] = bf16u_to_f32(src[s]);
            *(uint2*)(dstb + (size_t)k * M_DIM + g * 8) = pack8_fp8(f);
        }
    }
}

// ---------------- K2: GEMM2 fp8 (MX-scaled, scale=1.0), BK=64 ----------------
// part[logical_bid][kl][el] = sum_m pb[k][m]*xT[e][m]
// XCD-GROUP REMAP (R4): the 8 blocks {kt}x{et} sharing one m-window land on ONE XCD
// (same p%8) -> 1 fetch + 7 L2 hits. part[] indexed by LOGICAL bid; reduce_out unchanged.
__global__ __launch_bounds__(256) void gemm2(const unsigned char* __restrict__ pb8, const unsigned char* __restrict__ xT8,
                                             float* __restrict__ part) {
    int p_ = blockIdx.x;
    int xcd = p_ & 7, idx = p_ >> 3;
    int kt_et = idx & 7, cb = idx >> 3;          // cb 0..7
    int kt = kt_et & 1, et = kt_et >> 1;
    int c2 = (cb << 3) | xcd;                    // 0..63
    int ch = c2 & 31, b = c2 >> 5;
    int lbid = kt | (et << 1) | (ch << 3) | (b << 8);   // logical bid for part[]

    int t = threadIdx.x, lane = t & 63, w = t >> 6;
    int wk = w & 1, we = w >> 1;

    __shared__ __align__(16) unsigned char Alds[2][128 * 64];   // 2 x 8 KB
    __shared__ __align__(16) unsigned char Blds[2][128 * 64];   // 2 x 8 KB

    const unsigned char* Ab = pb8 + ((size_t)(b * K_DIM + kt * 128)) * M_DIM + ch * 2048;
    const unsigned char* Bb = xT8 + ((size_t)(b * E_DIM + et * 128)) * M_DIM + ch * 2048;

    f32x16 acc[2][2];
#pragma unroll
    for (int i = 0; i < 2; ++i)
#pragma unroll
        for (int j = 0; j < 2; ++j)
#pragma unroll
            for (int p = 0; p < 16; ++p) acc[i][j][p] = 0.f;

    int l31 = lane & 31, g = lane >> 5;

    auto STAGE = [&](int buf, int m0) {
#pragma unroll
        for (int is = 0; is < 2; ++is) {
            int c = is * 256 + t;          // 16B slot id 0..511, lane-linear LDS dst
            int row = c >> 2, a = c & 3;
            int sr = (row & 3) ^ ((row >> 2) & 3);
            int bsl = a ^ sr;              // phys slot a holds logical slot a^sr
            async_load16(Ab + (size_t)row * M_DIM + m0 + bsl * 16, &Alds[buf][c * 16]);
            async_load16(Bb + (size_t)row * M_DIM + m0 + bsl * 16, &Blds[buf][c * 16]);
        }
    };

    STAGE(0, 0);
    __syncthreads();                       // drain prologue staging

    for (int km = 0; km < 32; ++km) {
        int cur = km & 1;
        if (km + 1 < 32) STAGE(cur ^ 1, (km + 1) * 64);   // issue next tile early

        i32x8 av[2], bv[2];
#pragma unroll
        for (int i = 0; i < 2; ++i) {
            int r = wk * 64 + i * 32 + l31;
            int sr = (r & 3) ^ ((r >> 2) & 3);
            int4 lo = *(const int4*)(&Alds[cur][r * 64 + (((2 * g) ^ sr) * 16)]);
            int4 hi = *(const int4*)(&Alds[cur][r * 64 + (((2 * g + 1) ^ sr) * 16)]);
            av[i][0] = lo.x; av[i][1] = lo.y; av[i][2] = lo.z; av[i][3] = lo.w;
            av[i][4] = hi.x; av[i][5] = hi.y; av[i][6] = hi.z; av[i][7] = hi.w;
        }
#pragma unroll
        for (int j = 0; j < 2; ++j) {
            int r = we * 64 + j * 32 + l31;
            int sr = (r & 3) ^ ((r >> 2) & 3);
            int4 lo = *(const int4*)(&Blds[cur][r * 64 + (((2 * g) ^ sr) * 16)]);
            int4 hi = *(const int4*)(&Blds[cur][r * 64 + (((2 * g + 1) ^ sr) * 16)]);
            bv[j][0] = lo.x; bv[j][1] = lo.y; bv[j][2] = lo.z; bv[j][3] = lo.w;
            bv[j][4] = hi.x; bv[j][5] = hi.y; bv[j][6] = hi.z; bv[j][7] = hi.w;
        }

        __builtin_amdgcn_s_setprio(1);
#pragma unroll
        for (int i = 0; i < 2; ++i)
#pragma unroll
            for (int j = 0; j < 2; ++j)
                acc[i][j] = __builtin_amdgcn_mfma_scale_f32_32x32x64_f8f6f4(
                    av[i], bv[j], acc[i][j],
                    0 /*cbsz: fp8 e4m3*/, 0 /*blgp: fp8 e4m3*/,
                    0, 0x7f7f7f7f /*scale A = 1.0*/,
                    0, 0x7f7f7f7f /*scale B = 1.0*/);
        __builtin_amdgcn_s_setprio(0);

        __syncthreads();   // waves done reading buf[cur]; next-tile staging drained
    }

    // C/D 32x32 layout: col = lane&31, row = (reg&3) + 8*(reg>>2) + 4*(lane>>5)
    float* pp = part + (size_t)lbid * 16384;
#pragma unroll
    for (int i = 0; i < 2; ++i)
#pragma unroll
        for (int p = 0; p < 16; ++p) {
            int kl = wk * 64 + i * 32 + (p & 3) + 8 * (p >> 2) + 4 * g;
#pragma unroll
            for (int j = 0; j < 2; ++j) {
                int el = we * 64 + j * 32 + l31;
                pp[kl * 128 + el] = acc[i][j][p];
            }
        }
}

// ---------------- K3: reduce partials over 32 chunks, fused colsum, normalize ----------------
// psums TRANSPOSED [b][k][mt] -> colsum gather fully coalesced.
__global__ __launch_bounds__(256) void reduce_out(const float* __restrict__ part, const float* __restrict__ psums,
                                                  float* __restrict__ out) {
    int bid = blockIdx.x;
    int ehalf = bid & 1, k = (bid >> 1) & 255, b = bid >> 9;
    int t = threadIdx.x, lane = t & 63;

    const float* ps = psums + (size_t)b * K_DIM * 1024 + (size_t)k * 1024;
    float cs = 0.f;
#pragma unroll
    for (int c = 0; c < 4; ++c) cs += ps[c * 256 + t];
#pragma unroll
    for (int mask = 1; mask < 64; mask <<= 1) cs += __shfl_xor(cs, mask, 64);
    __shared__ float cspart[4];
    if (lane == 0) cspart[t >> 6] = cs;
    __syncthreads();
    float colsum = (cspart[0] + cspart[1]) + (cspart[2] + cspart[3]);

    int e = ehalf * 256 + t;
    int kt = k >> 7, kl = k & 127, et = e >> 7, el = e & 127;
    float s = 0.f;
#pragma unroll
    for (int ch = 0; ch < 32; ++ch) {
        int bid2 = kt | (et << 1) | (ch << 3) | (b << 8);
        s += part[(size_t)bid2 * 16384 + kl * 128 + el];
    }
    out[((size_t)(b * 256 + k)) * 512 + e] = s / colsum;
}

extern "C" void kernel_launch(void* const* d_in, const int* in_sizes, int n_in,
                              void* d_out, int out_size, void* d_ws, size_t ws_size,
                              hipStream_t stream) {
    (void)in_sizes; (void)n_in; (void)out_size; (void)ws_size;
    const float* x = (const float*)d_in[0];
    const float* W = (const float*)d_in[1];
    // d_in[2] (bias) provably cancels in softmax over m -> unused.

    char* ws = (char*)d_ws;
    unsigned char* xT8 = (unsigned char*)ws;               //  67,108,864 B
    bf16_t* Wb    = (bf16_t*)(ws + 67108864);              //     262,144 B
    unsigned char* pb8 = (unsigned char*)(ws + 67371008);  //  33,554,432 B
    float*  psums = (float*)(ws + 100925440);              //   2,097,152 B  [b][k][mt]
    float*  part  = (float*)(ws + 103022592);              //  33,554,432 B (512 logical bids x 16384)
    float*  out   = (float*)d_out;

    cast_w<<<128, 256, 0, stream>>>(W, Wb);
    gemm1_exp_t<<<2048, 256, 0, stream>>>(x, Wb, pb8, psums, xT8);
    gemm2<<<512, 256, 0, stream>>>(pb8, xT8, part);
    reduce_out<<<1024, 256, 0, stream>>>(part, psums, out);
}